// Round 1
// baseline (680.077 us; speedup 1.0000x reference)
//
#include <hip/hip_runtime.h>
#include <stdint.h>

typedef unsigned short u16;
typedef __bf16 bf16t;
typedef bf16t bf16x8 __attribute__((ext_vector_type(8)));
typedef float f32x4 __attribute__((ext_vector_type(4)));

#define DEV static __device__ __forceinline__

DEV u16 f2b(float f) {
  unsigned u = __float_as_uint(f);
  return (u16)((u + 0x7fffu + ((u >> 16) & 1u)) >> 16);
}
DEV float b2f(u16 h) { return __uint_as_float(((unsigned)h) << 16); }
DEV f32x4 fzero() { f32x4 v = {0.f, 0.f, 0.f, 0.f}; return v; }
DEV f32x4 mfma16(bf16x8 a, bf16x8 b, f32x4 c) {
  return __builtin_amdgcn_mfma_f32_16x16x32_bf16(a, b, c, 0, 0, 0);
}

// Problem constants
#define SEQ 1024
#define MEML 1024
#define BB 4
#define HH 1024
#define NHH 16
#define HDD 64
#define TOT 2048

// ------------------------- elementwise converts -------------------------

__global__ __launch_bounds__(256) void k_pack(const float* __restrict__ mem,
                                              const float* __restrict__ x,
                                              u16* __restrict__ full) {
  size_t id4 = (size_t)blockIdx.x * 256 + threadIdx.x;  // 2,097,152 total
  size_t base = id4 * 4;
  int t = (int)(base >> 12);          // B*H = 4096
  int rem = (int)(base & 4095);
  const float* src = (t < MEML) ? (mem + ((size_t)t << 12) + rem)
                                : (x + ((size_t)(t - MEML) << 12) + rem);
  float4 v = *(const float4*)src;
  ushort4 o;
  o.x = f2b(v.x); o.y = f2b(v.y); o.z = f2b(v.z); o.w = f2b(v.w);
  *(ushort4*)(full + base) = o;
}

__global__ __launch_bounds__(256) void k_cvt(const float* __restrict__ src,
                                             u16* __restrict__ dst, int n4) {
  int id = blockIdx.x * 256 + threadIdx.x;
  if (id >= n4) return;
  size_t base = (size_t)id * 4;
  float4 v = *(const float4*)(src + base);
  ushort4 o;
  o.x = f2b(v.x); o.y = f2b(v.y); o.z = f2b(v.z); o.w = f2b(v.w);
  *(ushort4*)(dst + base) = o;
}

// ------------------------- generic bf16 GEMM core -------------------------
// C[M,N] = A[M,K] @ Bt[N,K]^T ; A,Bt row-major bf16(u16); f32 accum.
// Tile BM x BN, K-step 32, 16x16x32 MFMA, waves arranged WAVES_M x WAVES_N.

template <int BM, int BN, int MF, int NF>
DEV void gemm_core(const u16* __restrict__ A, int lda, const u16* __restrict__ Bt,
                   int ldb, int K, f32x4 (&acc)[MF][NF]) {
  constexpr int WM = 16 * MF, WN = 16 * NF;
  constexpr int WAVES_M = BM / WM, WAVES_N = BN / WN;
  constexpr int THREADS = WAVES_M * WAVES_N * 64;
  constexpr int ITA = (BM * 4) / THREADS;
  constexpr int ITB = (BN * 4) / THREADS;
  __shared__ u16 As[BM * 40];   // 40-short rows (80B): 16B aligned, low bank conflict
  __shared__ u16 Bs[BN * 40];
  const int tid = threadIdx.x, lane = tid & 63, wave = tid >> 6;
  const int wm = wave / WAVES_N, wn = wave % WAVES_N;
#pragma unroll
  for (int fm = 0; fm < MF; ++fm)
#pragma unroll
    for (int fn = 0; fn < NF; ++fn) acc[fm][fn] = fzero();

  for (int k0 = 0; k0 < K; k0 += 32) {
    __syncthreads();
#pragma unroll
    for (int it = 0; it < ITA; ++it) {
      int c = tid + it * THREADS;
      int r = c >> 2, kc = c & 3;
      *(uint4*)(As + r * 40 + kc * 8) =
          *(const uint4*)(A + (size_t)r * lda + k0 + kc * 8);
    }
#pragma unroll
    for (int it = 0; it < ITB; ++it) {
      int c = tid + it * THREADS;
      int r = c >> 2, kc = c & 3;
      *(uint4*)(Bs + r * 40 + kc * 8) =
          *(const uint4*)(Bt + (size_t)r * ldb + k0 + kc * 8);
    }
    __syncthreads();
    bf16x8 af[MF], bfr[NF];
#pragma unroll
    for (int fm = 0; fm < MF; ++fm)
      af[fm] = *(const bf16x8*)(As + (wm * WM + fm * 16 + (lane & 15)) * 40 +
                                ((lane >> 4) << 3));
#pragma unroll
    for (int fn = 0; fn < NF; ++fn)
      bfr[fn] = *(const bf16x8*)(Bs + (wn * WN + fn * 16 + (lane & 15)) * 40 +
                                 ((lane >> 4) << 3));
#pragma unroll
    for (int fm = 0; fm < MF; ++fm)
#pragma unroll
      for (int fn = 0; fn < NF; ++fn)
        acc[fm][fn] = mfma16(af[fm], bfr[fn], acc[fm][fn]);
  }
}

template <int BM, int BN, int MF, int NF, class F>
DEV void epi_apply(f32x4 (&acc)[MF][NF], F&& f) {
  constexpr int WAVES_N = BN / (16 * NF);
  const int lane = threadIdx.x & 63, wave = threadIdx.x >> 6;
  const int wm = wave / WAVES_N, wn = wave % WAVES_N;
#pragma unroll
  for (int fm = 0; fm < MF; ++fm)
#pragma unroll
    for (int fn = 0; fn < NF; ++fn)
#pragma unroll
      for (int q = 0; q < 4; ++q) {
        int rl = wm * (16 * MF) + fm * 16 + ((lane >> 4) << 2) + q;
        int cl = wn * (16 * NF) + fn * 16 + (lane & 15);
        f(rl, cl, acc[fm][fn][q]);
      }
}

// ------------------------- GEMM wrappers -------------------------

// QKV: full[8192,1024] @ Wqkv[3072,1024]^T, scatter epilogue into qw,qr,k,vt
__global__ __launch_bounds__(256) void k_gemm_qkv(
    const u16* __restrict__ full, const u16* __restrict__ wqkv,
    const float* __restrict__ rwb, const float* __restrict__ rrb,
    u16* __restrict__ qw, u16* __restrict__ qr, u16* __restrict__ kk,
    u16* __restrict__ vt) {
  f32x4 acc[4][4];
  const u16* A = full + (size_t)blockIdx.x * 128 * 1024;
  const u16* Bt = wqkv + (size_t)blockIdx.y * 128 * 1024;
  gemm_core<128, 128, 4, 4>(A, 1024, Bt, 1024, 1024, acc);
  const int row0 = blockIdx.x * 128, col0 = blockIdx.y * 128;
  epi_apply<128, 128, 4, 4>(acc, [&](int rl, int cl, float v) {
    int grow = row0 + rl, gcol = col0 + cl;
    int t = grow >> 2, bb = grow & 3;
    int which = gcol >> 10, hd = gcol & 1023;
    int n = hd >> 6, d = hd & 63;
    if (which == 0) {
      if (t >= MEML) {
        int i = t - MEML;
        size_t o = ((size_t)(bb * NHH + n) * SEQ + i) * HDD + d;
        qw[o] = f2b(v + rwb[hd]);
        qr[o] = f2b(v + rrb[hd]);
      }
    } else if (which == 1) {
      kk[((size_t)(bb * NHH + n) * TOT + t) * HDD + d] = f2b(v);
    } else {
      vt[((size_t)(bb * NHH + n) * HDD + d) * TOT + t] = f2b(v);
    }
  });
}

// r_k: pos[2048,1024] @ Wr[1024,1024]^T -> rk[n][r][d]
__global__ __launch_bounds__(256) void k_gemm_rk(const u16* __restrict__ pos,
                                                 const u16* __restrict__ wr,
                                                 u16* __restrict__ rk) {
  f32x4 acc[4][4];
  const u16* A = pos + (size_t)blockIdx.x * 128 * 1024;
  const u16* Bt = wr + (size_t)blockIdx.y * 128 * 1024;
  gemm_core<128, 128, 4, 4>(A, 1024, Bt, 1024, 1024, acc);
  const int row0 = blockIdx.x * 128, col0 = blockIdx.y * 128;
  epi_apply<128, 128, 4, 4>(acc, [&](int rl, int cl, float v) {
    int r = row0 + rl, o = col0 + cl;
    int n = o >> 6, d = o & 63;
    rk[((size_t)n * TOT + r) * HDD + d] = f2b(v);
  });
}

// PV: P[NI,2048] @ Vt[64,2048]^T per (b,n) -> avec[s=i*4+b, n*64+d] (bf16)
__global__ __launch_bounds__(256) void k_gemm_pv(const u16* __restrict__ Sb,
                                                 const u16* __restrict__ vt,
                                                 u16* __restrict__ avec, int b,
                                                 int i0c, int NI) {
  f32x4 acc[4][2];
  const int n = blockIdx.y;
  const u16* A = Sb + ((size_t)n * NI + blockIdx.x * 128) * TOT;
  const u16* Bt = vt + ((size_t)(b * NHH + n) * HDD) * TOT;
  gemm_core<128, 64, 4, 2>(A, TOT, Bt, TOT, TOT, acc);
  const int ibase = i0c + blockIdx.x * 128;
  epi_apply<128, 64, 4, 2>(acc, [&](int rl, int cl, float v) {
    int i = ibase + rl;
    int srow = i * BB + b;
    avec[(size_t)srow * HH + n * HDD + cl] = f2b(v);
  });
}

// out: avec[4096,1024] @ Wo[1024,1024]^T + x -> y (f32)
__global__ __launch_bounds__(256) void k_gemm_out(const u16* __restrict__ avec,
                                                  const u16* __restrict__ wo,
                                                  const float* __restrict__ x,
                                                  float* __restrict__ y) {
  f32x4 acc[4][4];
  const u16* A = avec + (size_t)blockIdx.x * 128 * 1024;
  const u16* Bt = wo + (size_t)blockIdx.y * 128 * 1024;
  gemm_core<128, 128, 4, 4>(A, 1024, Bt, 1024, 1024, acc);
  const int row0 = blockIdx.x * 128, col0 = blockIdx.y * 128;
  epi_apply<128, 128, 4, 4>(acc, [&](int rl, int cl, float v) {
    size_t o = (size_t)(row0 + rl) * HH + (col0 + cl);
    y[o] = v + x[o];
  });
}

// ------------------------- fused score kernel -------------------------
// Per block: (b, n, 64-row i-tile). S[i,j] = (qw_i.k_j + qr_i.rk[j-i+1023]) / 8
// BD_pre computed per 64-wide r-tile via MFMA into a 2-slot LDS ring.

__global__ __launch_bounds__(256) void k_score(
    const u16* __restrict__ qw, const u16* __restrict__ qr,
    const u16* __restrict__ kk, const u16* __restrict__ rk,
    u16* __restrict__ Sb, int b, int i0c, int NI) {
  __shared__ u16 Ks[64 * 72];
  __shared__ u16 Rs[64 * 72];
  __shared__ float BDp[64][132];
  const int tid = threadIdx.x, lane = tid & 63, w = tid >> 6;
  const int n = blockIdx.y;
  const int i0 = i0c + blockIdx.x * 64;
  const int bn = b * NHH + n;
  const u16* qwb = qw + ((size_t)bn * SEQ + i0) * HDD;
  const u16* qrb = qr + ((size_t)bn * SEQ + i0) * HDD;
  const u16* kb = kk + (size_t)bn * TOT * HDD;
  const u16* rkb = rk + (size_t)n * TOT * HDD;
  u16* S = Sb + ((size_t)n * NI + (i0 - i0c)) * TOT;

  // per-wave Q fragments (rows w*16 .. w*16+15), kept in regs
  bf16x8 qwf[2], qrf[2];
#pragma unroll
  for (int ks = 0; ks < 2; ++ks) {
    int off = (w * 16 + (lane & 15)) * HDD + ks * 32 + ((lane >> 4) << 3);
    qwf[ks] = *(const bf16x8*)(qwb + off);
    qrf[ks] = *(const bf16x8*)(qrb + off);
  }

  const int m0 = (960 - i0) / 64;  // first r-tile index

  auto stageR = [&](int rt) {
    int rb = rt * 64;
    for (int c = tid; c < 512; c += 256) {
      int r = c >> 3, kc = c & 7;
      int rr = rb + r;
      if (rr > 2047) rr = 2047;  // clamp: garbage only feeds masked elems
      *(uint4*)(Rs + r * 72 + kc * 8) =
          *(const uint4*)(rkb + (size_t)rr * HDD + kc * 8);
    }
  };

  auto bdcomp = [&](int rt) {
    f32x4 bd[4];
#pragma unroll
    for (int fn = 0; fn < 4; ++fn) bd[fn] = fzero();
#pragma unroll
    for (int ks = 0; ks < 2; ++ks)
#pragma unroll
      for (int fn = 0; fn < 4; ++fn) {
        bf16x8 rf = *(const bf16x8*)(Rs + (fn * 16 + (lane & 15)) * 72 +
                                     ks * 32 + ((lane >> 4) << 3));
        bd[fn] = mfma16(qrf[ks], rf, bd[fn]);
      }
    int slot = (rt & 1) << 6;
#pragma unroll
    for (int fn = 0; fn < 4; ++fn)
#pragma unroll
      for (int q = 0; q < 4; ++q)
        BDp[w * 16 + ((lane >> 4) << 2) + q][slot + fn * 16 + (lane & 15)] =
            bd[fn][q];
  };

  stageR(m0);
  __syncthreads();
  bdcomp(m0);

  const int jtc = i0 / 64 + 17;
  for (int jt = 0; jt < jtc; ++jt) {
    const int rt = m0 + jt + 1;
    const int j0 = jt * 64;
    __syncthreads();
    for (int c = tid; c < 512; c += 256) {
      int r = c >> 3, kc = c & 7;
      *(uint4*)(Ks + r * 72 + kc * 8) =
          *(const uint4*)(kb + (size_t)(j0 + r) * HDD + kc * 8);
    }
    stageR(rt);
    __syncthreads();
    bdcomp(rt);

    f32x4 ac[4];
#pragma unroll
    for (int fn = 0; fn < 4; ++fn) ac[fn] = fzero();
#pragma unroll
    for (int ks = 0; ks < 2; ++ks)
#pragma unroll
      for (int fn = 0; fn < 4; ++fn) {
        bf16x8 kf = *(const bf16x8*)(Ks + (fn * 16 + (lane & 15)) * 72 +
                                     ks * 32 + ((lane >> 4) << 3));
        ac[fn] = mfma16(qwf[ks], kf, ac[fn]);
      }

    const int d0 = j0 - i0 + 1023;
#pragma unroll
    for (int fn = 0; fn < 4; ++fn)
#pragma unroll
      for (int q = 0; q < 4; ++q) {
        int di = w * 16 + ((lane >> 4) << 2) + q;
        int dj = fn * 16 + (lane & 15);
        int r = d0 + dj - di;
        float sv = (ac[fn][q] + BDp[di][r & 127]) * 0.125f;
        S[(size_t)di * TOT + j0 + dj] = f2b(sv);
      }
  }
}

// ------------------------- softmax (in-place, wave per row) -------------------------

__global__ __launch_bounds__(256) void k_softmax(u16* __restrict__ Sb, int i0c,
                                                 int NI) {
  const int w = threadIdx.x >> 6, lane = threadIdx.x & 63;
  const int row_lin = blockIdx.x * 4 + w;
  const int n = row_lin / NI, il = row_lin % NI;
  const int i = i0c + il;
  u16* S = Sb + ((size_t)n * NI + il) * TOT;
  const int jmax = i + MEML;
  const float NEGINF = -__builtin_inff();
  float vals[32];
  float mx = NEGINF;
  union { uint4 v; u16 h[8]; } u;
#pragma unroll
  for (int c = 0; c < 4; ++c) {
    int j8 = c * 64 + lane;
    u.v = *(const uint4*)(S + (size_t)j8 * 8);
#pragma unroll
    for (int e = 0; e < 8; ++e) {
      int j = j8 * 8 + e;
      float v = (j <= jmax) ? b2f(u.h[e]) : NEGINF;
      vals[c * 8 + e] = v;
      mx = fmaxf(mx, v);
    }
  }
#pragma unroll
  for (int off = 1; off < 64; off <<= 1) mx = fmaxf(mx, __shfl_xor(mx, off, 64));
  float sum = 0.f;
#pragma unroll
  for (int t = 0; t < 32; ++t) {
    float e = __expf(vals[t] - mx);
    vals[t] = e;
    sum += e;
  }
#pragma unroll
  for (int off = 1; off < 64; off <<= 1) sum += __shfl_xor(sum, off, 64);
  float inv = 1.f / sum;
#pragma unroll
  for (int c = 0; c < 4; ++c) {
    int j8 = c * 64 + lane;
#pragma unroll
    for (int e = 0; e < 8; ++e) u.h[e] = f2b(vals[c * 8 + e] * inv);
    *(uint4*)(S + (size_t)j8 * 8) = u.v;
  }
}

// ------------------------- residual + LayerNorm -------------------------

__global__ __launch_bounds__(256) void k_ln(const float* __restrict__ y,
                                            const float* __restrict__ lw,
                                            const float* __restrict__ lb,
                                            float* __restrict__ out) {
  const int row = blockIdx.x, tid = threadIdx.x;
  const float4 v = *(const float4*)(y + (size_t)row * HH + tid * 4);
  float s = v.x + v.y + v.z + v.w;
  float ss = v.x * v.x + v.y * v.y + v.z * v.z + v.w * v.w;
#pragma unroll
  for (int off = 1; off < 64; off <<= 1) {
    s += __shfl_xor(s, off, 64);
    ss += __shfl_xor(ss, off, 64);
  }
  __shared__ float red[8];
  const int w = tid >> 6, lane = tid & 63;
  if (lane == 0) { red[w] = s; red[4 + w] = ss; }
  __syncthreads();
  float tot = red[0] + red[1] + red[2] + red[3];
  float tss = red[4] + red[5] + red[6] + red[7];
  float mu = tot * (1.f / 1024.f);
  float var = tss * (1.f / 1024.f) - mu * mu;
  float rs = rsqrtf(var + 1e-5f);
  float4 wv = *(const float4*)(lw + tid * 4);
  float4 bv = *(const float4*)(lb + tid * 4);
  float4 o;
  o.x = (v.x - mu) * rs * wv.x + bv.x;
  o.y = (v.y - mu) * rs * wv.y + bv.y;
  o.z = (v.z - mu) * rs * wv.z + bv.z;
  o.w = (v.w - mu) * rs * wv.w + bv.w;
  *(float4*)(out + (size_t)row * HH + tid * 4) = o;
}

// ------------------------- launch -------------------------

extern "C" void kernel_launch(void* const* d_in, const int* in_sizes, int n_in,
                              void* d_out, int out_size, void* d_ws,
                              size_t ws_size, hipStream_t stream) {
  const float* x = (const float*)d_in[0];
  const float* pos = (const float*)d_in[1];
  const float* rwb = (const float*)d_in[2];
  const float* rrb = (const float*)d_in[3];
  // d_in[4] = attn_mask, recomputed analytically
  const float* mem = (const float*)d_in[5];
  const float* wqkv = (const float*)d_in[6];
  const float* wr = (const float*)d_in[7];
  const float* wo = (const float*)d_in[8];
  const float* lnw = (const float*)d_in[9];
  const float* lnb = (const float*)d_in[10];

  char* ws = (char*)d_ws;
  const size_t O_FULL = 0;              // 16,777,216 B (aliased by y later)
  const size_t O_WQKV = 16777216;       // 6,291,456
  const size_t O_WR = 23068672;         // 2,097,152
  const size_t O_WO = 25165824;         // 2,097,152
  const size_t O_POS = 27262976;        // 4,194,304
  const size_t O_QW = 31457280;         // 8,388,608
  const size_t O_QR = 39845888;         // 8,388,608
  const size_t O_K = 48234496;          // 16,777,216
  const size_t O_VT = 65011712;         // 16,777,216
  const size_t O_RK = 81788928;         // 4,194,304
  const size_t O_AVEC = 85983232;       // 8,388,608
  const size_t O_S = 94371840;

  u16* full = (u16*)(ws + O_FULL);
  u16* wqkv_b = (u16*)(ws + O_WQKV);
  u16* wr_b = (u16*)(ws + O_WR);
  u16* wo_b = (u16*)(ws + O_WO);
  u16* pos_b = (u16*)(ws + O_POS);
  u16* qw = (u16*)(ws + O_QW);
  u16* qr = (u16*)(ws + O_QR);
  u16* kk = (u16*)(ws + O_K);
  u16* vt = (u16*)(ws + O_VT);
  u16* rk = (u16*)(ws + O_RK);
  u16* avec = (u16*)(ws + O_AVEC);
  float* y = (float*)(ws + O_FULL);  // alias: full dead after QKV GEMM
  u16* Sb = (u16*)(ws + O_S);

  int NI = 1024;
  while (O_S + (size_t)NHH * NI * TOT * 2 > ws_size && NI > 128) NI >>= 1;
  if (O_S + (size_t)NHH * NI * TOT * 2 > ws_size) return;  // ws too small: fail visibly

  k_pack<<<8192, 256, 0, stream>>>(mem, x, full);
  k_cvt<<<3072, 256, 0, stream>>>(wqkv, wqkv_b, 786432);
  k_cvt<<<1024, 256, 0, stream>>>(wr, wr_b, 262144);
  k_cvt<<<1024, 256, 0, stream>>>(wo, wo_b, 262144);
  k_cvt<<<2048, 256, 0, stream>>>(pos, pos_b, 524288);

  k_gemm_qkv<<<dim3(64, 24), 256, 0, stream>>>(full, wqkv_b, rwb, rrb, qw, qr,
                                               kk, vt);
  k_gemm_rk<<<dim3(16, 8), 256, 0, stream>>>(pos_b, wr_b, rk);

  for (int b = 0; b < BB; ++b) {
    for (int ic = 0; ic < SEQ / NI; ++ic) {
      int i0c = ic * NI;
      k_score<<<dim3(NI / 64, NHH), 256, 0, stream>>>(qw, qr, kk, rk, Sb, b,
                                                      i0c, NI);
      k_softmax<<<dim3(NHH * NI / 4), 256, 0, stream>>>(Sb, i0c, NI);
      k_gemm_pv<<<dim3(NI / 128, NHH), 256, 0, stream>>>(Sb, vt, avec, b, i0c,
                                                         NI);
    }
  }

  k_gemm_out<<<dim3(32, 8), 256, 0, stream>>>(avec, wo_b, x, y);
  k_ln<<<4096, 256, 0, stream>>>(y, lnw, lnb, (float*)d_out);
}

// Round 2
// 485.449 us; speedup vs baseline: 1.4009x; 1.4009x over previous
//
#include <hip/hip_runtime.h>
#include <stdint.h>

typedef unsigned short u16;
typedef __bf16 bf16t;
typedef bf16t bf16x8 __attribute__((ext_vector_type(8)));
typedef float f32x4 __attribute__((ext_vector_type(4)));

#define DEV static __device__ __forceinline__

DEV u16 f2b(float f) {
  unsigned u = __float_as_uint(f);
  return (u16)((u + 0x7fffu + ((u >> 16) & 1u)) >> 16);
}
DEV float b2f(u16 h) { return __uint_as_float(((unsigned)h) << 16); }
DEV f32x4 fzero() { f32x4 v = {0.f, 0.f, 0.f, 0.f}; return v; }
DEV f32x4 mfma16(bf16x8 a, bf16x8 b, f32x4 c) {
  return __builtin_amdgcn_mfma_f32_16x16x32_bf16(a, b, c, 0, 0, 0);
}

// Problem constants
#define SEQ 1024
#define MEML 1024
#define BB 4
#define HH 1024
#define NHH 16
#define HDD 64
#define TOT 2048

// ------------------------- elementwise converts -------------------------

__global__ __launch_bounds__(256) void k_pack(const float* __restrict__ mem,
                                              const float* __restrict__ x,
                                              u16* __restrict__ full) {
  size_t id4 = (size_t)blockIdx.x * 256 + threadIdx.x;  // 2,097,152 total
  size_t base = id4 * 4;
  int t = (int)(base >> 12);          // B*H = 4096
  int rem = (int)(base & 4095);
  const float* src = (t < MEML) ? (mem + ((size_t)t << 12) + rem)
                                : (x + ((size_t)(t - MEML) << 12) + rem);
  float4 v = *(const float4*)src;
  ushort4 o;
  o.x = f2b(v.x); o.y = f2b(v.y); o.z = f2b(v.z); o.w = f2b(v.w);
  *(ushort4*)(full + base) = o;
}

__global__ __launch_bounds__(256) void k_cvt(const float* __restrict__ src,
                                             u16* __restrict__ dst, int n4) {
  int id = blockIdx.x * 256 + threadIdx.x;
  if (id >= n4) return;
  size_t base = (size_t)id * 4;
  float4 v = *(const float4*)(src + base);
  ushort4 o;
  o.x = f2b(v.x); o.y = f2b(v.y); o.z = f2b(v.z); o.w = f2b(v.w);
  *(ushort4*)(dst + base) = o;
}

// ------------------------- generic bf16 GEMM core -------------------------

template <int BM, int BN, int MF, int NF>
DEV void gemm_core(const u16* __restrict__ A, int lda, const u16* __restrict__ Bt,
                   int ldb, int K, f32x4 (&acc)[MF][NF]) {
  constexpr int WM = 16 * MF, WN = 16 * NF;
  constexpr int WAVES_M = BM / WM, WAVES_N = BN / WN;
  constexpr int THREADS = WAVES_M * WAVES_N * 64;
  constexpr int ITA = (BM * 4) / THREADS;
  constexpr int ITB = (BN * 4) / THREADS;
  __shared__ u16 As[BM * 40];
  __shared__ u16 Bs[BN * 40];
  const int tid = threadIdx.x, lane = tid & 63, wave = tid >> 6;
  const int wm = wave / WAVES_N, wn = wave % WAVES_N;
#pragma unroll
  for (int fm = 0; fm < MF; ++fm)
#pragma unroll
    for (int fn = 0; fn < NF; ++fn) acc[fm][fn] = fzero();

  for (int k0 = 0; k0 < K; k0 += 32) {
    __syncthreads();
#pragma unroll
    for (int it = 0; it < ITA; ++it) {
      int c = tid + it * THREADS;
      int r = c >> 2, kc = c & 3;
      *(uint4*)(As + r * 40 + kc * 8) =
          *(const uint4*)(A + (size_t)r * lda + k0 + kc * 8);
    }
#pragma unroll
    for (int it = 0; it < ITB; ++it) {
      int c = tid + it * THREADS;
      int r = c >> 2, kc = c & 3;
      *(uint4*)(Bs + r * 40 + kc * 8) =
          *(const uint4*)(Bt + (size_t)r * ldb + k0 + kc * 8);
    }
    __syncthreads();
    bf16x8 af[MF], bfr[NF];
#pragma unroll
    for (int fm = 0; fm < MF; ++fm)
      af[fm] = *(const bf16x8*)(As + (wm * WM + fm * 16 + (lane & 15)) * 40 +
                                ((lane >> 4) << 3));
#pragma unroll
    for (int fn = 0; fn < NF; ++fn)
      bfr[fn] = *(const bf16x8*)(Bs + (wn * WN + fn * 16 + (lane & 15)) * 40 +
                                 ((lane >> 4) << 3));
#pragma unroll
    for (int fm = 0; fm < MF; ++fm)
#pragma unroll
      for (int fn = 0; fn < NF; ++fn)
        acc[fm][fn] = mfma16(af[fm], bfr[fn], acc[fm][fn]);
  }
}

template <int BM, int BN, int MF, int NF, class F>
DEV void epi_apply(f32x4 (&acc)[MF][NF], F&& f) {
  constexpr int WAVES_N = BN / (16 * NF);
  const int lane = threadIdx.x & 63, wave = threadIdx.x >> 6;
  const int wm = wave / WAVES_N, wn = wave % WAVES_N;
#pragma unroll
  for (int fm = 0; fm < MF; ++fm)
#pragma unroll
    for (int fn = 0; fn < NF; ++fn)
#pragma unroll
      for (int q = 0; q < 4; ++q) {
        int rl = wm * (16 * MF) + fm * 16 + ((lane >> 4) << 2) + q;
        int cl = wn * (16 * NF) + fn * 16 + (lane & 15);
        f(rl, cl, acc[fm][fn][q]);
      }
}

// ------------------------- GEMM wrappers -------------------------

__global__ __launch_bounds__(256) void k_gemm_qkv(
    const u16* __restrict__ full, const u16* __restrict__ wqkv,
    const float* __restrict__ rwb, const float* __restrict__ rrb,
    u16* __restrict__ qw, u16* __restrict__ qr, u16* __restrict__ kk,
    u16* __restrict__ vt) {
  f32x4 acc[4][4];
  const u16* A = full + (size_t)blockIdx.x * 128 * 1024;
  const u16* Bt = wqkv + (size_t)blockIdx.y * 128 * 1024;
  gemm_core<128, 128, 4, 4>(A, 1024, Bt, 1024, 1024, acc);
  const int row0 = blockIdx.x * 128, col0 = blockIdx.y * 128;
  epi_apply<128, 128, 4, 4>(acc, [&](int rl, int cl, float v) {
    int grow = row0 + rl, gcol = col0 + cl;
    int t = grow >> 2, bb = grow & 3;
    int which = gcol >> 10, hd = gcol & 1023;
    int n = hd >> 6, d = hd & 63;
    if (which == 0) {
      if (t >= MEML) {
        int i = t - MEML;
        size_t o = ((size_t)(bb * NHH + n) * SEQ + i) * HDD + d;
        qw[o] = f2b(v + rwb[hd]);
        qr[o] = f2b(v + rrb[hd]);
      }
    } else if (which == 1) {
      kk[((size_t)(bb * NHH + n) * TOT + t) * HDD + d] = f2b(v);
    } else {
      vt[((size_t)(bb * NHH + n) * HDD + d) * TOT + t] = f2b(v);
    }
  });
}

__global__ __launch_bounds__(256) void k_gemm_rk(const u16* __restrict__ pos,
                                                 const u16* __restrict__ wr,
                                                 u16* __restrict__ rk) {
  f32x4 acc[4][4];
  const u16* A = pos + (size_t)blockIdx.x * 128 * 1024;
  const u16* Bt = wr + (size_t)blockIdx.y * 128 * 1024;
  gemm_core<128, 128, 4, 4>(A, 1024, Bt, 1024, 1024, acc);
  const int row0 = blockIdx.x * 128, col0 = blockIdx.y * 128;
  epi_apply<128, 128, 4, 4>(acc, [&](int rl, int cl, float v) {
    int r = row0 + rl, o = col0 + cl;
    int n = o >> 6, d = o & 63;
    rk[((size_t)n * TOT + r) * HDD + d] = f2b(v);
  });
}

__global__ __launch_bounds__(256) void k_gemm_out(const u16* __restrict__ avec,
                                                  const u16* __restrict__ wo,
                                                  const float* __restrict__ x,
                                                  float* __restrict__ y) {
  f32x4 acc[4][4];
  const u16* A = avec + (size_t)blockIdx.x * 128 * 1024;
  const u16* Bt = wo + (size_t)blockIdx.y * 128 * 1024;
  gemm_core<128, 128, 4, 4>(A, 1024, Bt, 1024, 1024, acc);
  const int row0 = blockIdx.x * 128, col0 = blockIdx.y * 128;
  epi_apply<128, 128, 4, 4>(acc, [&](int rl, int cl, float v) {
    size_t o = (size_t)(row0 + rl) * HH + (col0 + cl);
    y[o] = v + x[o];
  });
}

// ------------------------- fused flash attention -------------------------
// Block = (i-tile of 64 rows, head n, batch b). 4 waves; wave w owns rows
// w*16..w*16+15. Online softmax in registers; P staged per-wave in LDS
// (wave-private -> no barrier); V fragments read directly from vt[d][t].
// S[i,j] = (qw_i.k_j + qr_i.rk[j-i+1023]) * 0.125, masked j > i+MEM.

__global__ __launch_bounds__(256) void k_flash(
    const u16* __restrict__ qw, const u16* __restrict__ qr,
    const u16* __restrict__ kk, const u16* __restrict__ rk,
    const u16* __restrict__ vt, u16* __restrict__ avec) {
  __shared__ u16 Ks[64 * 72];
  __shared__ u16 Rs[64 * 72];
  __shared__ u16 BDp[64][136];   // bf16 ring: 128 cols + 8 pad
  __shared__ u16 Ps[4][16 * 72]; // per-wave P tile 16x64 (72-pad)
  const int tid = threadIdx.x, lane = tid & 63, w = tid >> 6;
  const int n = blockIdx.y, b = blockIdx.z;
  const int i0 = blockIdx.x * 64;
  const int bn = b * NHH + n;
  const u16* qwb = qw + ((size_t)bn * SEQ + i0) * HDD;
  const u16* qrb = qr + ((size_t)bn * SEQ + i0) * HDD;
  const u16* kb = kk + (size_t)bn * TOT * HDD;
  const u16* rkb = rk + (size_t)n * TOT * HDD;
  const u16* vtb = vt + (size_t)bn * HDD * TOT;

  // per-wave Q fragments (rows w*16 .. w*16+15) in regs
  bf16x8 qwf[2], qrf[2];
#pragma unroll
  for (int ks = 0; ks < 2; ++ks) {
    int off = (w * 16 + (lane & 15)) * HDD + ks * 32 + ((lane >> 4) << 3);
    qwf[ks] = *(const bf16x8*)(qwb + off);
    qrf[ks] = *(const bf16x8*)(qrb + off);
  }

  const float NEGINF = -__builtin_inff();
  f32x4 oacc[4];
#pragma unroll
  for (int db = 0; db < 4; ++db) oacc[db] = fzero();
  float mrow[4] = {NEGINF, NEGINF, NEGINF, NEGINF};
  float lrow[4] = {0.f, 0.f, 0.f, 0.f};

  const int m0 = (960 - i0) / 64;  // first r-tile index

  auto stageR = [&](int rt) {
    int rb = rt * 64;
    for (int c = tid; c < 512; c += 256) {
      int r = c >> 3, kc = c & 7;
      int rr = rb + r;
      if (rr > 2047) rr = 2047;  // clamp: garbage only feeds masked elems
      *(uint4*)(Rs + r * 72 + kc * 8) =
          *(const uint4*)(rkb + (size_t)rr * HDD + kc * 8);
    }
  };

  auto bdcomp = [&](int rt) {
    f32x4 bd[4];
#pragma unroll
    for (int fn = 0; fn < 4; ++fn) bd[fn] = fzero();
#pragma unroll
    for (int ks = 0; ks < 2; ++ks)
#pragma unroll
      for (int fn = 0; fn < 4; ++fn) {
        bf16x8 rf = *(const bf16x8*)(Rs + (fn * 16 + (lane & 15)) * 72 +
                                     ks * 32 + ((lane >> 4) << 3));
        bd[fn] = mfma16(qrf[ks], rf, bd[fn]);
      }
    int slot = (rt & 1) << 6;
#pragma unroll
    for (int fn = 0; fn < 4; ++fn)
#pragma unroll
      for (int q = 0; q < 4; ++q)
        BDp[w * 16 + ((lane >> 4) << 2) + q][slot + fn * 16 + (lane & 15)] =
            f2b(bd[fn][q]);
  };

  stageR(m0);
  __syncthreads();
  bdcomp(m0);

  const int jtc = i0 / 64 + 17;
  for (int jt = 0; jt < jtc; ++jt) {
    const int rt = m0 + jt + 1;
    const int j0 = jt * 64;
    __syncthreads();
    for (int c = tid; c < 512; c += 256) {
      int r = c >> 3, kc = c & 7;
      *(uint4*)(Ks + r * 72 + kc * 8) =
          *(const uint4*)(kb + (size_t)(j0 + r) * HDD + kc * 8);
    }
    stageR(rt);
    __syncthreads();
    bdcomp(rt);

    // content scores AC
    f32x4 ac[4];
#pragma unroll
    for (int fn = 0; fn < 4; ++fn) ac[fn] = fzero();
#pragma unroll
    for (int ks = 0; ks < 2; ++ks)
#pragma unroll
      for (int fn = 0; fn < 4; ++fn) {
        bf16x8 kf = *(const bf16x8*)(Ks + (fn * 16 + (lane & 15)) * 72 +
                                     ks * 32 + ((lane >> 4) << 3));
        ac[fn] = mfma16(qwf[ks], kf, ac[fn]);
      }

    // assemble S (in ac), track new row max
    const int d0 = j0 - i0 + 1023;
    float mnew[4];
#pragma unroll
    for (int q = 0; q < 4; ++q) mnew[q] = mrow[q];
#pragma unroll
    for (int fn = 0; fn < 4; ++fn)
#pragma unroll
      for (int q = 0; q < 4; ++q) {
        int di = w * 16 + ((lane >> 4) << 2) + q;
        int dj = fn * 16 + (lane & 15);
        int r = d0 + dj - di;
        float sv = (ac[fn][q] + b2f(BDp[di][r & 127])) * 0.125f;
        if (j0 + dj > i0 + di + MEML) sv = NEGINF;
        ac[fn][q] = sv;
        mnew[q] = fmaxf(mnew[q], sv);
      }
    // reduce max across the 16-lane column group (rows preserved)
#pragma unroll
    for (int q = 0; q < 4; ++q) {
#pragma unroll
      for (int off = 1; off < 16; off <<= 1)
        mnew[q] = fmaxf(mnew[q], __shfl_xor(mnew[q], off, 64));
    }
    float scale[4];
#pragma unroll
    for (int q = 0; q < 4; ++q) {
      scale[q] = __expf(mrow[q] - mnew[q]);  // exp(-inf - finite) = 0
      mrow[q] = mnew[q];
      lrow[q] *= scale[q];
    }
    // P = exp(S - m); partial row sums stay per-lane (reduced at end)
#pragma unroll
    for (int fn = 0; fn < 4; ++fn)
#pragma unroll
      for (int q = 0; q < 4; ++q) {
        float p = __expf(ac[fn][q] - mrow[q]);
        lrow[q] += p;
        int row_l = ((lane >> 4) << 2) + q;
        Ps[w][row_l * 72 + fn * 16 + (lane & 15)] = f2b(p);
      }
    // rescale O
#pragma unroll
    for (int db = 0; db < 4; ++db)
#pragma unroll
      for (int q = 0; q < 4; ++q) oacc[db][q] *= scale[q];
    // PV: A = wave-local P from LDS, B = V frags straight from vt[d][t]
#pragma unroll
    for (int ks = 0; ks < 2; ++ks) {
      bf16x8 pa = *(const bf16x8*)(Ps[w] + (lane & 15) * 72 + ks * 32 +
                                   ((lane >> 4) << 3));
#pragma unroll
      for (int db = 0; db < 4; ++db) {
        bf16x8 vf = *(const bf16x8*)(vtb + (size_t)(db * 16 + (lane & 15)) * TOT +
                                     j0 + ks * 32 + ((lane >> 4) << 3));
        oacc[db] = mfma16(pa, vf, oacc[db]);
      }
    }
  }

  // final: full row sums, normalize, write avec
#pragma unroll
  for (int q = 0; q < 4; ++q) {
#pragma unroll
    for (int off = 1; off < 16; off <<= 1) lrow[q] += __shfl_xor(lrow[q], off, 64);
    lrow[q] = 1.f / lrow[q];
  }
#pragma unroll
  for (int db = 0; db < 4; ++db)
#pragma unroll
    for (int q = 0; q < 4; ++q) {
      int i = i0 + w * 16 + ((lane >> 4) << 2) + q;
      avec[((size_t)i * BB + b) * HH + n * HDD + db * 16 + (lane & 15)] =
          f2b(oacc[db][q] * lrow[q]);
    }
}

// ------------------------- residual + LayerNorm -------------------------

__global__ __launch_bounds__(256) void k_ln(const float* __restrict__ y,
                                            const float* __restrict__ lw,
                                            const float* __restrict__ lb,
                                            float* __restrict__ out) {
  const int row = blockIdx.x, tid = threadIdx.x;
  const float4 v = *(const float4*)(y + (size_t)row * HH + tid * 4);
  float s = v.x + v.y + v.z + v.w;
  float ss = v.x * v.x + v.y * v.y + v.z * v.z + v.w * v.w;
#pragma unroll
  for (int off = 1; off < 64; off <<= 1) {
    s += __shfl_xor(s, off, 64);
    ss += __shfl_xor(ss, off, 64);
  }
  __shared__ float red[8];
  const int w = tid >> 6, lane = tid & 63;
  if (lane == 0) { red[w] = s; red[4 + w] = ss; }
  __syncthreads();
  float tot = red[0] + red[1] + red[2] + red[3];
  float tss = red[4] + red[5] + red[6] + red[7];
  float mu = tot * (1.f / 1024.f);
  float var = tss * (1.f / 1024.f) - mu * mu;
  float rs = rsqrtf(var + 1e-5f);
  float4 wv = *(const float4*)(lw + tid * 4);
  float4 bv = *(const float4*)(lb + tid * 4);
  float4 o;
  o.x = (v.x - mu) * rs * wv.x + bv.x;
  o.y = (v.y - mu) * rs * wv.y + bv.y;
  o.z = (v.z - mu) * rs * wv.z + bv.z;
  o.w = (v.w - mu) * rs * wv.w + bv.w;
  *(float4*)(out + (size_t)row * HH + tid * 4) = o;
}

// ------------------------- launch -------------------------

extern "C" void kernel_launch(void* const* d_in, const int* in_sizes, int n_in,
                              void* d_out, int out_size, void* d_ws,
                              size_t ws_size, hipStream_t stream) {
  const float* x = (const float*)d_in[0];
  const float* pos = (const float*)d_in[1];
  const float* rwb = (const float*)d_in[2];
  const float* rrb = (const float*)d_in[3];
  // d_in[4] = attn_mask, recomputed analytically
  const float* mem = (const float*)d_in[5];
  const float* wqkv = (const float*)d_in[6];
  const float* wr = (const float*)d_in[7];
  const float* wo = (const float*)d_in[8];
  const float* lnw = (const float*)d_in[9];
  const float* lnb = (const float*)d_in[10];

  char* ws = (char*)d_ws;
  const size_t O_FULL = 0;              // 16,777,216 B (aliased by y later)
  const size_t O_WQKV = 16777216;       // 6,291,456
  const size_t O_WR = 23068672;         // 2,097,152
  const size_t O_WO = 25165824;         // 2,097,152
  const size_t O_POS = 27262976;        // 4,194,304
  const size_t O_QW = 31457280;         // 8,388,608
  const size_t O_QR = 39845888;         // 8,388,608
  const size_t O_K = 48234496;          // 16,777,216
  const size_t O_VT = 65011712;         // 16,777,216
  const size_t O_RK = 81788928;         // 4,194,304
  const size_t O_AVEC = 85983232;       // 8,388,608
  const size_t NEED = 94371840;

  if (ws_size < NEED) return;  // fail visibly

  u16* full = (u16*)(ws + O_FULL);
  u16* wqkv_b = (u16*)(ws + O_WQKV);
  u16* wr_b = (u16*)(ws + O_WR);
  u16* wo_b = (u16*)(ws + O_WO);
  u16* pos_b = (u16*)(ws + O_POS);
  u16* qw = (u16*)(ws + O_QW);
  u16* qr = (u16*)(ws + O_QR);
  u16* kk = (u16*)(ws + O_K);
  u16* vt = (u16*)(ws + O_VT);
  u16* rk = (u16*)(ws + O_RK);
  u16* avec = (u16*)(ws + O_AVEC);
  float* y = (float*)(ws + O_FULL);  // alias: full dead after QKV GEMM

  k_pack<<<8192, 256, 0, stream>>>(mem, x, full);
  k_cvt<<<3072, 256, 0, stream>>>(wqkv, wqkv_b, 786432);
  k_cvt<<<1024, 256, 0, stream>>>(wr, wr_b, 262144);
  k_cvt<<<1024, 256, 0, stream>>>(wo, wo_b, 262144);
  k_cvt<<<2048, 256, 0, stream>>>(pos, pos_b, 524288);

  k_gemm_qkv<<<dim3(64, 24), 256, 0, stream>>>(full, wqkv_b, rwb, rrb, qw, qr,
                                               kk, vt);
  k_gemm_rk<<<dim3(16, 8), 256, 0, stream>>>(pos_b, wr_b, rk);

  k_flash<<<dim3(16, NHH, BB), 256, 0, stream>>>(qw, qr, kk, rk, vt, avec);

  k_gemm_out<<<dim3(32, 8), 256, 0, stream>>>(avec, wo_b, x, y);
  k_ln<<<4096, 256, 0, stream>>>(y, lnw, lnb, (float*)d_out);
}